// Round 17
// baseline (127.774 us; speedup 1.0000x reference)
//
#include <hip/hip_runtime.h>
#include <hip/hip_bf16.h>
#include <math.h>

// Problem constants
#define BB 4
#define SS 2048
#define DD 512
#define HH 8
#define DHH 64
#define DFF 2048
#define MM (BB*SS)          // 8192 rows
#define QKV_N (3*DD)        // 1536

typedef float  f32x4  __attribute__((ext_vector_type(4)));
typedef __bf16 bf16x8 __attribute__((ext_vector_type(8)));
typedef unsigned short us8 __attribute__((ext_vector_type(8)));
typedef unsigned short us4 __attribute__((ext_vector_type(4)));

// ---- bf16 helpers (RNE, finite inputs) ----
__device__ __forceinline__ unsigned short f2bf(float v) {
    unsigned int u = __float_as_uint(v);
    unsigned int r = (u + 0x7fffu + ((u >> 16) & 1u)) >> 16;
    return (unsigned short)r;
}
__device__ __forceinline__ float bf2f(unsigned short h) {
    return __uint_as_float(((unsigned int)h) << 16);
}

__device__ __forceinline__ f32x4 mfma_bf16(us8 a, us8 b, f32x4 c) {
    return __builtin_amdgcn_mfma_f32_16x16x32_bf16(
        __builtin_bit_cast(bf16x8, a), __builtin_bit_cast(bf16x8, b), c, 0, 0, 0);
}

// NOTE: imm offset of global_load_lds applies to BOTH global and LDS addresses
// (round-9 NaN post-mortem) — always pass 0 and advance pointers instead.
__device__ __forceinline__ void gload_lds16(const void* gsrc, void* ldst) {
    __builtin_amdgcn_global_load_lds(
        (const __attribute__((address_space(1))) void*)gsrc,
        (__attribute__((address_space(3))) void*)ldst, 16, 0, 0);
}

// ---------------------------------------------------------------- LayerNorm (fp32 in) -> bf16
__global__ __launch_bounds__(128)
void ln_kernel(const float* __restrict__ x, const float* __restrict__ g,
               const float* __restrict__ beta, unsigned short* __restrict__ outp)
{
    const int row = blockIdx.x;
    const int t = threadIdx.x;               // 128 threads, 4 floats each
    const float4 v = reinterpret_cast<const float4*>(x + (size_t)row * DD)[t];

    float s  = v.x + v.y + v.z + v.w;
    float s2 = v.x*v.x + v.y*v.y + v.z*v.z + v.w*v.w;
    #pragma unroll
    for (int off = 32; off >= 1; off >>= 1) {
        s  += __shfl_xor(s,  off);
        s2 += __shfl_xor(s2, off);
    }
    __shared__ float red[2][2];
    const int lane = t & 63, wid = t >> 6;
    if (lane == 0) { red[wid][0] = s; red[wid][1] = s2; }
    __syncthreads();
    const float ts  = red[0][0] + red[1][0];
    const float ts2 = red[0][1] + red[1][1];
    const float mu  = ts * (1.0f / DD);
    const float var = ts2 * (1.0f / DD) - mu * mu;
    const float rs  = rsqrtf(var + 1e-5f);

    const float4 gv = reinterpret_cast<const float4*>(g)[t];
    const float4 bv = reinterpret_cast<const float4*>(beta)[t];
    us4 hv;
    hv[0] = f2bf((v.x - mu) * rs * gv.x + bv.x);
    hv[1] = f2bf((v.y - mu) * rs * gv.y + bv.y);
    hv[2] = f2bf((v.z - mu) * rs * gv.z + bv.z);
    hv[3] = f2bf((v.w - mu) * rs * gv.w + bv.w);
    *reinterpret_cast<us4*>(outp + (size_t)row * DD + t * 4) = hv;
}

// ---------------------------------------------------------------- LayerNorm (bf16 in) -> bf16
__global__ __launch_bounds__(128)
void ln_kernel_b(const unsigned short* __restrict__ x, const float* __restrict__ g,
                 const float* __restrict__ beta, unsigned short* __restrict__ outp)
{
    const int row = blockIdx.x;
    const int t = threadIdx.x;               // 128 threads, 4 bf16 each
    const us4 hv_in = reinterpret_cast<const us4*>(x + (size_t)row * DD)[t];
    float v0 = bf2f(hv_in[0]), v1 = bf2f(hv_in[1]), v2 = bf2f(hv_in[2]), v3 = bf2f(hv_in[3]);

    float s  = v0 + v1 + v2 + v3;
    float s2 = v0*v0 + v1*v1 + v2*v2 + v3*v3;
    #pragma unroll
    for (int off = 32; off >= 1; off >>= 1) {
        s  += __shfl_xor(s,  off);
        s2 += __shfl_xor(s2, off);
    }
    __shared__ float red[2][2];
    const int lane = t & 63, wid = t >> 6;
    if (lane == 0) { red[wid][0] = s; red[wid][1] = s2; }
    __syncthreads();
    const float ts  = red[0][0] + red[1][0];
    const float ts2 = red[0][1] + red[1][1];
    const float mu  = ts * (1.0f / DD);
    const float var = ts2 * (1.0f / DD) - mu * mu;
    const float rs  = rsqrtf(var + 1e-5f);

    const float4 gv = reinterpret_cast<const float4*>(g)[t];
    const float4 bv = reinterpret_cast<const float4*>(beta)[t];
    us4 hv;
    hv[0] = f2bf((v0 - mu) * rs * gv.x + bv.x);
    hv[1] = f2bf((v1 - mu) * rs * gv.y + bv.y);
    hv[2] = f2bf((v2 - mu) * rs * gv.z + bv.z);
    hv[3] = f2bf((v3 - mu) * rs * gv.w + bv.w);
    *reinterpret_cast<us4*>(outp + (size_t)row * DD + t * 4) = hv;
}

// ---------------------------------------------------------------- fp32 -> bf16 weights (one launch)
__global__ __launch_bounds__(256)
void conv_all(const float* __restrict__ w_in, const float* __restrict__ w_out,
              const float* __restrict__ w_ff1, const float* __restrict__ w_ff2,
              unsigned short* __restrict__ dst3, unsigned short* __restrict__ dstw2)
{
    const int gid = blockIdx.x * 256 + threadIdx.x;
    const float* src;
    unsigned short* dst;
    size_t o;
    if (gid < 262144) {
        const int r  = gid >> 6;
        const int k0 = (gid & 63) * 8;
        src = (r < 1536) ? w_in  + (size_t)r * 512 + k0
            : (r < 2048) ? w_out + (size_t)(r - 1536) * 512 + k0
                         : w_ff1 + (size_t)(r - 2048) * 512 + k0;
        o = (size_t)r * 512 + k0;
        dst = dst3;
    } else {
        const int g  = gid - 262144;
        const int r  = g >> 8;
        const int k0 = (g & 255) * 8;
        src = w_ff2 + (size_t)r * 2048 + k0;
        o = (size_t)r * 2048 + k0;
        dst = dstw2;
    }
    us8 h;
    #pragma unroll
    for (int i = 0; i < 8; ++i) h[i] = f2bf(src[i]);
    *reinterpret_cast<us8*>(dst + o) = h;
}

// ---------------------------------------------------------------- BK=32 bf16 GEMM (all four GEMMs)
// BM=128, BN in {128, 64}, BK=32. LDS/buf = 8KB A + BN*64B B:
//   BN=128: 16KB/buf -> 32KB dbuf -> 4 blocks/CU (16 waves)
//   BN=64 : 12KB/buf -> 24KB dbuf -> 5-6 blocks/CU (20-24 waves)
// K-tile = 32 elems = 64B/row = 4 chunks of 16B; swizzle slot = chunk ^ (row&3).
// 2-barrier dbuf loop, x2-unrolled, static buffer indices, persistent pointers.
// XCD-aware bijective block swizzle (requires nwg % 8 == 0).
// EPI: 2 = bias+GELU -> bf16 Cs; 3 = bias -> bf16 Cs;
//      4 = bias+Resf(fp32) -> bf16 Cs; 5 = bias+Resh(bf16) -> fp32 Cf
template<int BN, int EPI>
__global__ __launch_bounds__(256, 4)
void gemm_k32(const unsigned short* __restrict__ Ax, const unsigned short* __restrict__ Wx,
              const float* __restrict__ bias,
              const float* __restrict__ Resf, const unsigned short* __restrict__ Resh,
              float* __restrict__ Cf, unsigned short* __restrict__ Cs,
              int N, int K)
{
    constexpr int NF   = BN / 32;          // n-frags per wave (4 or 2)
    constexpr int BL   = BN / 64;          // B stage loads per thread (2 or 1)
    constexpr int AUSH = 128 * 32;         // 4096 ush = 8 KB
    constexpr int BUSH = BN * 32;
    __shared__ unsigned short smem[2][AUSH + BUSH];

    const int tid  = threadIdx.x;
    const int wave = tid >> 6, lane = tid & 63;
    const int wm = wave >> 1, wn = wave & 1;
    const int lr = lane & 15, kc = lane >> 4;

    const int nwg = gridDim.x * gridDim.y;
    int bid = blockIdx.y * gridDim.x + blockIdx.x;
    bid = (bid & 7) * (nwg >> 3) + (bid >> 3);
    const int bn = (bid % gridDim.x) * BN;
    const int bm = (bid / gridDim.x) * 128;

    const int nkb = K >> 5;                // 16 (K=512) or 64 (K=2048) — even

    int aoff[4], woff[NF];
    #pragma unroll
    for (int m = 0; m < 4; ++m) {
        const int ra = wm * 64 + m * 16 + lr;
        aoff[m] = ra * 32 + ((kc ^ (ra & 3)) * 8);
    }
    #pragma unroll
    for (int n = 0; n < NF; ++n) {
        const int rw = wn * (NF * 16) + n * 16 + lr;
        woff[n] = AUSH + rw * 32 + ((kc ^ (rw & 3)) * 8);
    }

    f32x4 acc[4][NF];
    #pragma unroll
    for (int i = 0; i < 4; ++i)
        #pragma unroll
        for (int j = 0; j < NF; ++j) acc[i][j] = (f32x4){0.f, 0.f, 0.f, 0.f};

    // persistent staging pointers; source chunk = LDS slot ^ (row&3)
    const unsigned short* aP[2];
    const unsigned short* wP[BL];
    #pragma unroll
    for (int j = 0; j < 2; ++j) {
        const int off = j * 2048 + tid * 8;
        const int row = off >> 5;
        const int q   = ((off >> 3) & 3) ^ (row & 3);
        aP[j] = Ax + (size_t)(bm + row) * K + q * 8;
    }
    #pragma unroll
    for (int j = 0; j < BL; ++j) {
        const int off = j * 2048 + tid * 8;
        const int row = off >> 5;
        const int q   = ((off >> 3) & 3) ^ (row & 3);
        wP[j] = Wx + (size_t)(bn + row) * K + q * 8;
    }

#define STAGE_T(BUF) do {                                                      \
        _Pragma("unroll")                                                      \
        for (int j = 0; j < 2; ++j)                                            \
            gload_lds16(aP[j], &smem[BUF][j * 2048 + tid * 8]);                \
        _Pragma("unroll")                                                      \
        for (int j = 0; j < BL; ++j)                                           \
            gload_lds16(wP[j], &smem[BUF][AUSH + j * 2048 + tid * 8]);         \
    } while (0)

#define ADV_T() do {                                                           \
        _Pragma("unroll")                                                      \
        for (int j = 0; j < 2; ++j) aP[j] += 32;                               \
        _Pragma("unroll")                                                      \
        for (int j = 0; j < BL; ++j) wP[j] += 32;                              \
    } while (0)

#define COMPUTE_T(BUF) do {                                                    \
        const unsigned short* S = smem[BUF];                                   \
        us8 a[4], w[NF];                                                       \
        _Pragma("unroll")                                                      \
        for (int m = 0; m < 4; ++m)                                            \
            a[m] = *reinterpret_cast<const us8*>(S + aoff[m]);                 \
        _Pragma("unroll")                                                      \
        for (int n = 0; n < NF; ++n)                                           \
            w[n] = *reinterpret_cast<const us8*>(S + woff[n]);                 \
        _Pragma("unroll")                                                      \
        for (int m = 0; m < 4; ++m)                                            \
            _Pragma("unroll")                                                  \
            for (int n = 0; n < NF; ++n)                                       \
                acc[m][n] = mfma_bf16(a[m], w[n], acc[m][n]);                  \
    } while (0)

    STAGE_T(0); ADV_T();
    for (int kb = 0; kb < nkb; kb += 2) {
        __syncthreads();                            // buf0 arrived; prev buf1 readers done
        STAGE_T(1); ADV_T();                        // tile kb+1 -> buf1
        COMPUTE_T(0);                               // tile kb
        __syncthreads();                            // buf1 arrived; buf0 readers done
        if (kb + 2 < nkb) STAGE_T(0);               // tile kb+2 -> buf0
        ADV_T();
        COMPUTE_T(1);                               // tile kb+1
    }
#undef STAGE_T
#undef ADV_T
#undef COMPUTE_T

    // epilogue; C/D layout: col = lane&15, row = (lane>>4)*4 + reg
    float bvn[NF];
    #pragma unroll
    for (int n = 0; n < NF; ++n) bvn[n] = bias[bn + wn * (NF * 16) + n * 16 + lr];

    #pragma unroll
    for (int m = 0; m < 4; ++m) {
        #pragma unroll
        for (int j = 0; j < 4; ++j) {
            const int row = bm + wm * 64 + m * 16 + kc * 4 + j;
            #pragma unroll
            for (int n = 0; n < NF; ++n) {
                const int col = bn + wn * (NF * 16) + n * 16 + lr;
                float v = acc[m][n][j] + bvn[n];
                if constexpr (EPI == 2) {
                    v = 0.5f * v * (1.0f + erff(v * 0.70710678118654752f));
                    Cs[(size_t)row * N + col] = f2bf(v);
                } else if constexpr (EPI == 3) {
                    Cs[(size_t)row * N + col] = f2bf(v);
                } else if constexpr (EPI == 4) {
                    v += Resf[(size_t)row * N + col];
                    Cs[(size_t)row * N + col] = f2bf(v);
                } else {   // EPI == 5
                    v += bf2f(Resh[(size_t)row * N + col]);
                    Cf[(size_t)row * N + col] = v;
                }
            }
        }
    }
}

// ---------------------------------------------------------------- Local attention (bf16 qkv in, bf16 out)
__global__ __launch_bounds__(256)
void attn_kernel(const unsigned short* __restrict__ qkv, unsigned short* __restrict__ ctx)
{
    constexpr int RAD = 4;
    constexpr int TQ  = 64;
    constexpr int KROWS = TQ + 2 * RAD;   // 72
    constexpr int LDK = DHH + 4;          // 68

    __shared__ float Ks[KROWS][LDK];
    __shared__ float Vs[KROWS][LDK];

    const int t  = threadIdx.x;
    const int qt = blockIdx.x;
    const int b  = blockIdx.y;
    const int h  = blockIdx.z;
    const int q0 = qt * TQ;
    const unsigned short* base = qkv + (size_t)(b * SS) * QKV_N + h * DHH;

    for (int idx = t; idx < KROWS * 8; idx += 256) {
        const int row = idx >> 3;
        const int c8  = idx & 7;              // 8 elems per unit
        const int gr  = q0 - RAD + row;
        float kf[8], vf[8];
        if (gr >= 0 && gr < SS) {
            const unsigned short* p = base + (size_t)gr * QKV_N;
            const us8 kv = *reinterpret_cast<const us8*>(p + DD     + c8 * 8);
            const us8 vv = *reinterpret_cast<const us8*>(p + 2 * DD + c8 * 8);
            #pragma unroll
            for (int i = 0; i < 8; ++i) { kf[i] = bf2f(kv[i]); vf[i] = bf2f(vv[i]); }
        } else {
            #pragma unroll
            for (int i = 0; i < 8; ++i) { kf[i] = 0.f; vf[i] = 0.f; }
        }
        #pragma unroll
        for (int i = 0; i < 8; i += 4) {
            *reinterpret_cast<float4*>(&Ks[row][c8 * 8 + i]) =
                make_float4(kf[i], kf[i+1], kf[i+2], kf[i+3]);
            *reinterpret_cast<float4*>(&Vs[row][c8 * 8 + i]) =
                make_float4(vf[i], vf[i+1], vf[i+2], vf[i+3]);
        }
    }
    __syncthreads();

    const int qi   = t >> 2;
    const int quad = t & 3;
    const int gq   = q0 + qi;
    const int d0   = quad * 16;

    const unsigned short* qp = base + (size_t)gq * QKV_N + d0;
    float q[16];
    {
        const us8 qa = *reinterpret_cast<const us8*>(qp);
        const us8 qb = *reinterpret_cast<const us8*>(qp + 8);
        #pragma unroll
        for (int i = 0; i < 8; ++i) { q[i] = bf2f(qa[i]); q[8 + i] = bf2f(qb[i]); }
    }

    float s[9];
    #pragma unroll
    for (int j = 0; j < 9; ++j) {
        const float* kr = &Ks[qi + j][d0];
        float p = 0.f;
        #pragma unroll
        for (int i = 0; i < 16; i += 4) {
            const float4 k4 = *reinterpret_cast<const float4*>(kr + i);
            p += q[i] * k4.x + q[i+1] * k4.y + q[i+2] * k4.z + q[i+3] * k4.w;
        }
        p += __shfl_xor(p, 1);
        p += __shfl_xor(p, 2);
        const int gk = gq + j - RAD;
        s[j] = (gk >= 0 && gk < SS) ? p * 0.125f : -INFINITY;
    }
    float mx = s[0];
    #pragma unroll
    for (int j = 1; j < 9; ++j) mx = fmaxf(mx, s[j]);
    float pr[9]; float l = 0.f;
    #pragma unroll
    for (int j = 0; j < 9; ++j) { pr[j] = __expf(s[j] - mx); l += pr[j]; }
    const float inv = 1.0f / l;

    float o[16];
    #pragma unroll
    for (int i = 0; i < 16; ++i) o[i] = 0.f;
    #pragma unroll
    for (int j = 0; j < 9; ++j) {
        const float pj = pr[j] * inv;
        const float* vr = &Vs[qi + j][d0];
        #pragma unroll
        for (int i = 0; i < 16; i += 4) {
            const float4 v4 = *reinterpret_cast<const float4*>(vr + i);
            o[i]     = fmaf(pj, v4.x, o[i]);
            o[i + 1] = fmaf(pj, v4.y, o[i + 1]);
            o[i + 2] = fmaf(pj, v4.z, o[i + 2]);
            o[i + 3] = fmaf(pj, v4.w, o[i + 3]);
        }
    }
    unsigned short* op = ctx + (size_t)(b * SS + gq) * DD + h * DHH + d0;
    us8 h0, h1;
    #pragma unroll
    for (int i = 0; i < 8; ++i) {
        h0[i] = f2bf(o[i]);
        h1[i] = f2bf(o[8 + i]);
    }
    *reinterpret_cast<us8*>(op)     = h0;
    *reinterpret_cast<us8*>(op + 8) = h1;
}

// ---------------------------------------------------------------- launch
extern "C" void kernel_launch(void* const* d_in, const int* in_sizes, int n_in,
                              void* d_out, int out_size, void* d_ws, size_t ws_size,
                              hipStream_t stream)
{
    const float* x     = (const float*)d_in[0];
    const float* w_in  = (const float*)d_in[1];
    const float* b_in  = (const float*)d_in[2];
    const float* w_out = (const float*)d_in[3];
    const float* b_out = (const float*)d_in[4];
    const float* w_ff1 = (const float*)d_in[5];
    const float* b_ff1 = (const float*)d_in[6];
    const float* w_ff2 = (const float*)d_in[7];
    const float* b_ff2 = (const float*)d_in[8];
    const float* ln1_g = (const float*)d_in[9];
    const float* ln1_b = (const float*)d_in[10];
    const float* ln2_g = (const float*)d_in[11];
    const float* ln2_b = (const float*)d_in[12];
    float* out = (float*)d_out;

    // workspace layout (bytes):
    // [0,16M)    lnq   bf16 [8192][512]   (LN out, reused for LN2)
    // [16M,32M)  x1    bf16 [8192][512]   (8 MB)
    // [32M,48M)  ctxs  bf16 [8192][512]   (dead before ffh written)
    // [32M,64M)  ffh   bf16 [8192][2048]  (step 6, over dead ctxs/qkv)
    // [48M,72M)  qkv   bf16 [8192][1536]  (dead after step 3)
    // [99.1M..]  weights bf16 (wqs|wos|w1s contiguous, then w2s)
    char* ws = (char*)d_ws;
    unsigned short* lnq  = (unsigned short*)ws;
    unsigned short* x1h  = (unsigned short*)(ws + 16777216);
    unsigned short* ctxs = (unsigned short*)(ws + 2 * 16777216);
    unsigned short* qkv  = (unsigned short*)(ws + 3 * 16777216);
    unsigned short* ffh  = (unsigned short*)(ws + 2 * 16777216);
    unsigned short* wqs  = (unsigned short*)(ws + 2 * 16777216 + 67108864);
    unsigned short* wos  = wqs + (size_t)1536 * 512;
    unsigned short* w1s  = wos + (size_t)512 * 512;
    unsigned short* w2s  = w1s + (size_t)2048 * 512;

    // weight conversions: one launch for all four weights
    conv_all<<<1536, 256, 0, stream>>>(w_in, w_out, w_ff1, w_ff2, wqs, w2s);

    // 1. LN1 -> bf16
    ln_kernel<<<MM, 128, 0, stream>>>(x, ln1_g, ln1_b, lnq);

    // 2. QKV -> bf16 qkv   (BN=128: grid 768, 4 blocks/CU)
    gemm_k32<128, 3><<<dim3(QKV_N / 128, MM / 128), 256, 0, stream>>>(
        lnq, wqs, b_in, nullptr, nullptr, nullptr, qkv, QKV_N, 512);

    // 3. local attention -> bf16 ctx
    attn_kernel<<<dim3(SS / 64, BB, HH), 256, 0, stream>>>(qkv, ctxs);

    // 4. out-proj + residual: x1 = bf16(x + ctx @ out_w^T + b)   (BN=64: grid 512, 5-6 blocks/CU)
    gemm_k32<64, 4><<<dim3(DD / 64, MM / 128), 256, 0, stream>>>(
        ctxs, wos, b_out, x, nullptr, nullptr, x1h, DD, 512);

    // 5. LN2 (bf16 in) -> bf16
    ln_kernel_b<<<MM, 128, 0, stream>>>(x1h, ln2_g, ln2_b, lnq);

    // 6. FF1 + GELU -> bf16 ffh   (BN=128: grid 1024)
    gemm_k32<128, 2><<<dim3(DFF / 128, MM / 128), 256, 0, stream>>>(
        lnq, w1s, b_ff1, nullptr, nullptr, nullptr, ffh, DFF, 512);

    // 7. FF2 + residual: out = bf2f(x1) + ffh @ ff_w2^T + b   (BN=64: grid 512, K=2048)
    gemm_k32<64, 5><<<dim3(DD / 64, MM / 128), 256, 0, stream>>>(
        ffh, w2s, b_ff2, nullptr, x1h, out, nullptr, DD, 2048);
}

// Round 18
// 120.900 us; speedup vs baseline: 1.0569x; 1.0569x over previous
//
#include <hip/hip_runtime.h>
#include <hip/hip_bf16.h>
#include <math.h>

// Problem constants
#define BB 4
#define SS 2048
#define DD 512
#define HH 8
#define DHH 64
#define DFF 2048
#define MM (BB*SS)          // 8192 rows
#define QKV_N (3*DD)        // 1536

typedef float  f32x4  __attribute__((ext_vector_type(4)));
typedef __bf16 bf16x8 __attribute__((ext_vector_type(8)));
typedef unsigned short us8 __attribute__((ext_vector_type(8)));
typedef unsigned short us4 __attribute__((ext_vector_type(4)));

// ---- bf16 helpers (RNE, finite inputs) ----
__device__ __forceinline__ unsigned short f2bf(float v) {
    unsigned int u = __float_as_uint(v);
    unsigned int r = (u + 0x7fffu + ((u >> 16) & 1u)) >> 16;
    return (unsigned short)r;
}
__device__ __forceinline__ float bf2f(unsigned short h) {
    return __uint_as_float(((unsigned int)h) << 16);
}

__device__ __forceinline__ f32x4 mfma_bf16(us8 a, us8 b, f32x4 c) {
    return __builtin_amdgcn_mfma_f32_16x16x32_bf16(
        __builtin_bit_cast(bf16x8, a), __builtin_bit_cast(bf16x8, b), c, 0, 0, 0);
}

// NOTE: imm offset of global_load_lds applies to BOTH global and LDS addresses
// (round-9 NaN post-mortem) — always pass 0 and advance pointers instead.
__device__ __forceinline__ void gload_lds16(const void* gsrc, void* ldst) {
    __builtin_amdgcn_global_load_lds(
        (const __attribute__((address_space(1))) void*)gsrc,
        (__attribute__((address_space(3))) void*)ldst, 16, 0, 0);
}

// ---------------------------------------------------------------- LayerNorm (fp32 in) -> bf16
__global__ __launch_bounds__(128)
void ln_kernel(const float* __restrict__ x, const float* __restrict__ g,
               const float* __restrict__ beta, unsigned short* __restrict__ outp)
{
    const int row = blockIdx.x;
    const int t = threadIdx.x;               // 128 threads, 4 floats each
    const float4 v = reinterpret_cast<const float4*>(x + (size_t)row * DD)[t];

    float s  = v.x + v.y + v.z + v.w;
    float s2 = v.x*v.x + v.y*v.y + v.z*v.z + v.w*v.w;
    #pragma unroll
    for (int off = 32; off >= 1; off >>= 1) {
        s  += __shfl_xor(s,  off);
        s2 += __shfl_xor(s2, off);
    }
    __shared__ float red[2][2];
    const int lane = t & 63, wid = t >> 6;
    if (lane == 0) { red[wid][0] = s; red[wid][1] = s2; }
    __syncthreads();
    const float ts  = red[0][0] + red[1][0];
    const float ts2 = red[0][1] + red[1][1];
    const float mu  = ts * (1.0f / DD);
    const float var = ts2 * (1.0f / DD) - mu * mu;
    const float rs  = rsqrtf(var + 1e-5f);

    const float4 gv = reinterpret_cast<const float4*>(g)[t];
    const float4 bv = reinterpret_cast<const float4*>(beta)[t];
    us4 hv;
    hv[0] = f2bf((v.x - mu) * rs * gv.x + bv.x);
    hv[1] = f2bf((v.y - mu) * rs * gv.y + bv.y);
    hv[2] = f2bf((v.z - mu) * rs * gv.z + bv.z);
    hv[3] = f2bf((v.w - mu) * rs * gv.w + bv.w);
    *reinterpret_cast<us4*>(outp + (size_t)row * DD + t * 4) = hv;
}

// ---------------------------------------------------------------- LayerNorm (bf16 in) -> bf16
__global__ __launch_bounds__(128)
void ln_kernel_b(const unsigned short* __restrict__ x, const float* __restrict__ g,
                 const float* __restrict__ beta, unsigned short* __restrict__ outp)
{
    const int row = blockIdx.x;
    const int t = threadIdx.x;               // 128 threads, 4 bf16 each
    const us4 hv_in = reinterpret_cast<const us4*>(x + (size_t)row * DD)[t];
    float v0 = bf2f(hv_in[0]), v1 = bf2f(hv_in[1]), v2 = bf2f(hv_in[2]), v3 = bf2f(hv_in[3]);

    float s  = v0 + v1 + v2 + v3;
    float s2 = v0*v0 + v1*v1 + v2*v2 + v3*v3;
    #pragma unroll
    for (int off = 32; off >= 1; off >>= 1) {
        s  += __shfl_xor(s,  off);
        s2 += __shfl_xor(s2, off);
    }
    __shared__ float red[2][2];
    const int lane = t & 63, wid = t >> 6;
    if (lane == 0) { red[wid][0] = s; red[wid][1] = s2; }
    __syncthreads();
    const float ts  = red[0][0] + red[1][0];
    const float ts2 = red[0][1] + red[1][1];
    const float mu  = ts * (1.0f / DD);
    const float var = ts2 * (1.0f / DD) - mu * mu;
    const float rs  = rsqrtf(var + 1e-5f);

    const float4 gv = reinterpret_cast<const float4*>(g)[t];
    const float4 bv = reinterpret_cast<const float4*>(beta)[t];
    us4 hv;
    hv[0] = f2bf((v0 - mu) * rs * gv.x + bv.x);
    hv[1] = f2bf((v1 - mu) * rs * gv.y + bv.y);
    hv[2] = f2bf((v2 - mu) * rs * gv.z + bv.z);
    hv[3] = f2bf((v3 - mu) * rs * gv.w + bv.w);
    *reinterpret_cast<us4*>(outp + (size_t)row * DD + t * 4) = hv;
}

// ---------------------------------------------------------------- fp32 -> bf16 weights (one launch)
__global__ __launch_bounds__(256)
void conv_all(const float* __restrict__ w_in, const float* __restrict__ w_out,
              const float* __restrict__ w_ff1, const float* __restrict__ w_ff2,
              unsigned short* __restrict__ dst3, unsigned short* __restrict__ dstw2)
{
    const int gid = blockIdx.x * 256 + threadIdx.x;
    const float* src;
    unsigned short* dst;
    size_t o;
    if (gid < 262144) {
        const int r  = gid >> 6;
        const int k0 = (gid & 63) * 8;
        src = (r < 1536) ? w_in  + (size_t)r * 512 + k0
            : (r < 2048) ? w_out + (size_t)(r - 1536) * 512 + k0
                         : w_ff1 + (size_t)(r - 2048) * 512 + k0;
        o = (size_t)r * 512 + k0;
        dst = dst3;
    } else {
        const int g  = gid - 262144;
        const int r  = g >> 8;
        const int k0 = (g & 255) * 8;
        src = w_ff2 + (size_t)r * 2048 + k0;
        o = (size_t)r * 2048 + k0;
        dst = dstw2;
    }
    us8 h;
    #pragma unroll
    for (int i = 0; i < 8; ++i) h[i] = f2bf(src[i]);
    *reinterpret_cast<us8*>(dst + o) = h;
}

// ---------------------------------------------------------------- BK=32 BN=128 bf16 GEMM (QKV, FF1)
// BM=128, BN=128, BK=32: 32KB LDS dbuf -> 4 blocks/CU (16 waves).
// Swizzle FIXED (round-17 post-mortem): chunk = kc ^ ((row>>2)&3). At BK=32 the
// row term in the bank index is (row*16)%32 ∈ {0,16}; XOR by (row>>2)&3 gives
// 8 distinct start banks x 2 lanes = 2-way (free, m136). Old (row&3) XOR left
// rows {r,r+4,r+8,r+12} in the same bank -> 4-way, 2.1M conflicts measured.
// EPI: 2 = bias+GELU -> bf16 Cs; 3 = bias -> bf16 Cs
template<int EPI>
__global__ __launch_bounds__(256, 4)
void gemm_k32(const unsigned short* __restrict__ Ax, const unsigned short* __restrict__ Wx,
              const float* __restrict__ bias, unsigned short* __restrict__ Cs,
              int N, int K)
{
    constexpr int AUSH = 128 * 32;         // 4096 ush = 8 KB
    __shared__ unsigned short smem[2][2 * AUSH];

    const int tid  = threadIdx.x;
    const int wave = tid >> 6, lane = tid & 63;
    const int wm = wave >> 1, wn = wave & 1;
    const int lr = lane & 15, kc = lane >> 4;

    const int nwg = gridDim.x * gridDim.y;
    int bid = blockIdx.y * gridDim.x + blockIdx.x;
    bid = (bid & 7) * (nwg >> 3) + (bid >> 3);
    const int bn = (bid % gridDim.x) * 128;
    const int bm = (bid / gridDim.x) * 128;

    const int nkb = K >> 5;                // 16 for K=512 (even)

    int aoff[4], woff[4];
    #pragma unroll
    for (int m = 0; m < 4; ++m) {
        const int ra = wm * 64 + m * 16 + lr;
        aoff[m] = ra * 32 + ((kc ^ ((ra >> 2) & 3)) * 8);
    }
    #pragma unroll
    for (int n = 0; n < 4; ++n) {
        const int rw = wn * 64 + n * 16 + lr;
        woff[n] = AUSH + rw * 32 + ((kc ^ ((rw >> 2) & 3)) * 8);
    }

    f32x4 acc[4][4];
    #pragma unroll
    for (int i = 0; i < 4; ++i)
        #pragma unroll
        for (int j = 0; j < 4; ++j) acc[i][j] = (f32x4){0.f, 0.f, 0.f, 0.f};

    // staging pointers; source chunk = LDS slot ^ ((row>>2)&3)
    const unsigned short* aP[2];
    const unsigned short* wP[2];
    #pragma unroll
    for (int j = 0; j < 2; ++j) {
        const int off = j * 2048 + tid * 8;
        const int row = off >> 5;
        const int q   = ((off >> 3) & 3) ^ ((row >> 2) & 3);
        aP[j] = Ax + (size_t)(bm + row) * K + q * 8;
        wP[j] = Wx + (size_t)(bn + row) * K + q * 8;
    }

#define STAGE_T(BUF) do {                                                      \
        _Pragma("unroll")                                                      \
        for (int j = 0; j < 2; ++j) {                                          \
            gload_lds16(aP[j], &smem[BUF][j * 2048 + tid * 8]);                \
            gload_lds16(wP[j], &smem[BUF][AUSH + j * 2048 + tid * 8]);         \
        }                                                                      \
    } while (0)

#define ADV_T() do {                                                           \
        _Pragma("unroll")                                                      \
        for (int j = 0; j < 2; ++j) { aP[j] += 32; wP[j] += 32; }              \
    } while (0)

#define COMPUTE_T(BUF) do {                                                    \
        const unsigned short* S = smem[BUF];                                   \
        us8 a[4], w[4];                                                        \
        _Pragma("unroll")                                                      \
        for (int m = 0; m < 4; ++m)                                            \
            a[m] = *reinterpret_cast<const us8*>(S + aoff[m]);                 \
        _Pragma("unroll")                                                      \
        for (int n = 0; n < 4; ++n)                                            \
            w[n] = *reinterpret_cast<const us8*>(S + woff[n]);                 \
        _Pragma("unroll")                                                      \
        for (int m = 0; m < 4; ++m)                                            \
            _Pragma("unroll")                                                  \
            for (int n = 0; n < 4; ++n)                                        \
                acc[m][n] = mfma_bf16(a[m], w[n], acc[m][n]);                  \
    } while (0)

    STAGE_T(0); ADV_T();
    for (int kb = 0; kb < nkb; kb += 2) {
        __syncthreads();
        STAGE_T(1); ADV_T();
        COMPUTE_T(0);
        __syncthreads();
        if (kb + 2 < nkb) STAGE_T(0);
        ADV_T();
        COMPUTE_T(1);
    }
#undef STAGE_T
#undef ADV_T
#undef COMPUTE_T

    // epilogue; C/D layout: col = lane&15, row = (lane>>4)*4 + reg
    float bvn[4];
    #pragma unroll
    for (int n = 0; n < 4; ++n) bvn[n] = bias[bn + wn * 64 + n * 16 + lr];

    #pragma unroll
    for (int m = 0; m < 4; ++m) {
        #pragma unroll
        for (int j = 0; j < 4; ++j) {
            const int row = bm + wm * 64 + m * 16 + kc * 4 + j;
            #pragma unroll
            for (int n = 0; n < 4; ++n) {
                const int col = bn + wn * 64 + n * 16 + lr;
                float v = acc[m][n][j] + bvn[n];
                if constexpr (EPI == 2)
                    v = 0.5f * v * (1.0f + erff(v * 0.70710678118654752f));
                Cs[(size_t)row * N + col] = f2bf(v);
            }
        }
    }
}

// ---------------------------------------------------------------- BN=64 BK=64 bf16 GEMM (oproj, FF2)
// Conflict-free swizzle (8 chunks: bank = chunk*4, spans all banks; measured 0
// conflicts rounds 13-16). 48KB LDS -> 3 blocks/CU. 2-barrier dbuf, x2-unrolled.
// EPI: 4 = bias + Resf(fp32) -> bf16 Cs; 5 = bias + Resh(bf16) -> fp32 Cf
template<int BN, int EPI>
__global__ __launch_bounds__(256, 3)
void gemm_tile(const unsigned short* __restrict__ Ax, const unsigned short* __restrict__ Wx,
               const float* __restrict__ bias,
               const float* __restrict__ Resf, const unsigned short* __restrict__ Resh,
               float* __restrict__ Cf, unsigned short* __restrict__ Cs,
               int N, int K)
{
    constexpr int NF   = BN / 32;
    constexpr int NB   = BN / 32;
    constexpr int AUSH = 128 * 64;
    constexpr int BUSH = BN * 64;
    __shared__ unsigned short smem[2][AUSH + BUSH];

    const int tid  = threadIdx.x;
    const int wave = tid >> 6, lane = tid & 63;
    const int wm = wave >> 1, wn = wave & 1;
    const int lr = lane & 15, kc = lane >> 4;

    const int nwg = gridDim.x * gridDim.y;
    int bid = blockIdx.y * gridDim.x + blockIdx.x;
    bid = (bid & 7) * (nwg >> 3) + (bid >> 3);
    const int bn = (bid % gridDim.x) * BN;
    const int bm = (bid / gridDim.x) * 128;

    const int nkb = K >> 6;

    int aoff[4], woff[NF];
    #pragma unroll
    for (int m = 0; m < 4; ++m) {
        const int ra = wm * 64 + m * 16 + lr;
        aoff[m] = ra * 64 + ((kc ^ (ra & 7)) * 8);
    }
    #pragma unroll
    for (int n = 0; n < NF; ++n) {
        const int rw = wn * (NF * 16) + n * 16 + lr;
        woff[n] = AUSH + rw * 64 + ((kc ^ (rw & 7)) * 8);
    }

    f32x4 acc[4][NF];
    #pragma unroll
    for (int i = 0; i < 4; ++i)
        #pragma unroll
        for (int j = 0; j < NF; ++j) acc[i][j] = (f32x4){0.f, 0.f, 0.f, 0.f};

    const unsigned short* aP[4];
    const unsigned short* wP[NB];
    #pragma unroll
    for (int j = 0; j < 4; ++j) {
        const int off = j * 2048 + tid * 8;
        const int row = off >> 6;
        const int q   = ((off >> 3) & 7) ^ (row & 7);
        aP[j] = Ax + (size_t)(bm + row) * K + q * 8;
    }
    #pragma unroll
    for (int j = 0; j < NB; ++j) {
        const int off = j * 2048 + tid * 8;
        const int row = off >> 6;
        const int q   = ((off >> 3) & 7) ^ (row & 7);
        wP[j] = Wx + (size_t)(bn + row) * K + q * 8;
    }

#define STAGE_T(BUF) do {                                                      \
        _Pragma("unroll")                                                      \
        for (int j = 0; j < 4; ++j)                                            \
            gload_lds16(aP[j], &smem[BUF][j * 2048 + tid * 8]);                \
        _Pragma("unroll")                                                      \
        for (int j = 0; j < NB; ++j)                                           \
            gload_lds16(wP[j], &smem[BUF][AUSH + j * 2048 + tid * 8]);         \
    } while (0)

#define ADV_T() do {                                                           \
        _Pragma("unroll")                                                      \
        for (int j = 0; j < 4; ++j) aP[j] += 64;                               \
        _Pragma("unroll")                                                      \
        for (int j = 0; j < NB; ++j) wP[j] += 64;                              \
    } while (0)

#define COMPUTE_T(BUF) do {                                                    \
        const unsigned short* S = smem[BUF];                                   \
        us8 a0[4], a1[4], w0[NF], w1[NF];                                      \
        _Pragma("unroll")                                                      \
        for (int m = 0; m < 4; ++m) {                                          \
            a0[m] = *reinterpret_cast<const us8*>(S + aoff[m]);                \
            a1[m] = *reinterpret_cast<const us8*>(S + (aoff[m] ^ 32));         \
        }                                                                      \
        _Pragma("unroll")                                                      \
        for (int n = 0; n < NF; ++n) {                                         \
            w0[n] = *reinterpret_cast<const us8*>(S + woff[n]);                \
            w1[n] = *reinterpret_cast<const us8*>(S + (woff[n] ^ 32));         \
        }                                                                      \
        _Pragma("unroll")                                                      \
        for (int m = 0; m < 4; ++m)                                            \
            _Pragma("unroll")                                                  \
            for (int n = 0; n < NF; ++n) {                                     \
                acc[m][n] = mfma_bf16(a0[m], w0[n], acc[m][n]);                \
                acc[m][n] = mfma_bf16(a1[m], w1[n], acc[m][n]);                \
            }                                                                  \
    } while (0)

    STAGE_T(0); ADV_T();
    for (int kb = 0; kb < nkb; kb += 2) {
        __syncthreads();
        STAGE_T(1); ADV_T();
        COMPUTE_T(0);
        __syncthreads();
        if (kb + 2 < nkb) STAGE_T(0);
        ADV_T();
        COMPUTE_T(1);
    }
#undef STAGE_T
#undef ADV_T
#undef COMPUTE_T

    float bvn[NF];
    #pragma unroll
    for (int n = 0; n < NF; ++n) bvn[n] = bias[bn + wn * (NF * 16) + n * 16 + lr];

    #pragma unroll
    for (int m = 0; m < 4; ++m) {
        #pragma unroll
        for (int j = 0; j < 4; ++j) {
            const int row = bm + wm * 64 + m * 16 + kc * 4 + j;
            #pragma unroll
            for (int n = 0; n < NF; ++n) {
                const int col = bn + wn * (NF * 16) + n * 16 + lr;
                float v = acc[m][n][j] + bvn[n];
                if constexpr (EPI == 4) {
                    v += Resf[(size_t)row * N + col];
                    Cs[(size_t)row * N + col] = f2bf(v);
                } else {   // EPI == 5
                    v += bf2f(Resh[(size_t)row * N + col]);
                    Cf[(size_t)row * N + col] = v;
                }
            }
        }
    }
}

// ---------------------------------------------------------------- Local attention (bf16 qkv in, bf16 out)
__global__ __launch_bounds__(256)
void attn_kernel(const unsigned short* __restrict__ qkv, unsigned short* __restrict__ ctx)
{
    constexpr int RAD = 4;
    constexpr int TQ  = 64;
    constexpr int KROWS = TQ + 2 * RAD;   // 72
    constexpr int LDK = DHH + 4;          // 68

    __shared__ float Ks[KROWS][LDK];
    __shared__ float Vs[KROWS][LDK];

    const int t  = threadIdx.x;
    const int qt = blockIdx.x;
    const int b  = blockIdx.y;
    const int h  = blockIdx.z;
    const int q0 = qt * TQ;
    const unsigned short* base = qkv + (size_t)(b * SS) * QKV_N + h * DHH;

    for (int idx = t; idx < KROWS * 8; idx += 256) {
        const int row = idx >> 3;
        const int c8  = idx & 7;              // 8 elems per unit
        const int gr  = q0 - RAD + row;
        float kf[8], vf[8];
        if (gr >= 0 && gr < SS) {
            const unsigned short* p = base + (size_t)gr * QKV_N;
            const us8 kv = *reinterpret_cast<const us8*>(p + DD     + c8 * 8);
            const us8 vv = *reinterpret_cast<const us8*>(p + 2 * DD + c8 * 8);
            #pragma unroll
            for (int i = 0; i < 8; ++i) { kf[i] = bf2f(kv[i]); vf[i] = bf2f(vv[i]); }
        } else {
            #pragma unroll
            for (int i = 0; i < 8; ++i) { kf[i] = 0.f; vf[i] = 0.f; }
        }
        #pragma unroll
        for (int i = 0; i < 8; i += 4) {
            *reinterpret_cast<float4*>(&Ks[row][c8 * 8 + i]) =
                make_float4(kf[i], kf[i+1], kf[i+2], kf[i+3]);
            *reinterpret_cast<float4*>(&Vs[row][c8 * 8 + i]) =
                make_float4(vf[i], vf[i+1], vf[i+2], vf[i+3]);
        }
    }
    __syncthreads();

    const int qi   = t >> 2;
    const int quad = t & 3;
    const int gq   = q0 + qi;
    const int d0   = quad * 16;

    const unsigned short* qp = base + (size_t)gq * QKV_N + d0;
    float q[16];
    {
        const us8 qa = *reinterpret_cast<const us8*>(qp);
        const us8 qb = *reinterpret_cast<const us8*>(qp + 8);
        #pragma unroll
        for (int i = 0; i < 8; ++i) { q[i] = bf2f(qa[i]); q[8 + i] = bf2f(qb[i]); }
    }

    float s[9];
    #pragma unroll
    for (int j = 0; j < 9; ++j) {
        const float* kr = &Ks[qi + j][d0];
        float p = 0.f;
        #pragma unroll
        for (int i = 0; i < 16; i += 4) {
            const float4 k4 = *reinterpret_cast<const float4*>(kr + i);
            p += q[i] * k4.x + q[i+1] * k4.y + q[i+2] * k4.z + q[i+3] * k4.w;
        }
        p += __shfl_xor(p, 1);
        p += __shfl_xor(p, 2);
        const int gk = gq + j - RAD;
        s[j] = (gk >= 0 && gk < SS) ? p * 0.125f : -INFINITY;
    }
    float mx = s[0];
    #pragma unroll
    for (int j = 1; j < 9; ++j) mx = fmaxf(mx, s[j]);
    float pr[9]; float l = 0.f;
    #pragma unroll
    for (int j = 0; j < 9; ++j) { pr[j] = __expf(s[j] - mx); l += pr[j]; }
    const float inv = 1.0f / l;

    float o[16];
    #pragma unroll
    for (int i = 0; i < 16; ++i) o[i] = 0.f;
    #pragma unroll
    for (int j = 0; j < 9; ++j) {
        const float pj = pr[j] * inv;
        const float* vr = &Vs[qi + j][d0];
        #pragma unroll
        for (int i = 0; i < 16; i += 4) {
            const float4 v4 = *reinterpret_cast<const float4*>(vr + i);
            o[i]     = fmaf(pj, v4.x, o[i]);
            o[i + 1] = fmaf(pj, v4.y, o[i + 1]);
            o[i + 2] = fmaf(pj, v4.z, o[i + 2]);
            o[i + 3] = fmaf(pj, v4.w, o[i + 3]);
        }
    }
    unsigned short* op = ctx + (size_t)(b * SS + gq) * DD + h * DHH + d0;
    us8 h0, h1;
    #pragma unroll
    for (int i = 0; i < 8; ++i) {
        h0[i] = f2bf(o[i]);
        h1[i] = f2bf(o[8 + i]);
    }
    *reinterpret_cast<us8*>(op)     = h0;
    *reinterpret_cast<us8*>(op + 8) = h1;
}

// ---------------------------------------------------------------- launch
extern "C" void kernel_launch(void* const* d_in, const int* in_sizes, int n_in,
                              void* d_out, int out_size, void* d_ws, size_t ws_size,
                              hipStream_t stream)
{
    const float* x     = (const float*)d_in[0];
    const float* w_in  = (const float*)d_in[1];
    const float* b_in  = (const float*)d_in[2];
    const float* w_out = (const float*)d_in[3];
    const float* b_out = (const float*)d_in[4];
    const float* w_ff1 = (const float*)d_in[5];
    const float* b_ff1 = (const float*)d_in[6];
    const float* w_ff2 = (const float*)d_in[7];
    const float* b_ff2 = (const float*)d_in[8];
    const float* ln1_g = (const float*)d_in[9];
    const float* ln1_b = (const float*)d_in[10];
    const float* ln2_g = (const float*)d_in[11];
    const float* ln2_b = (const float*)d_in[12];
    float* out = (float*)d_out;

    // workspace layout (bytes):
    // [0,16M)    lnq   bf16 [8192][512]   (LN out, reused for LN2)
    // [16M,32M)  x1    bf16 [8192][512]
    // [32M,48M)  ctxs  bf16 [8192][512]   (dead before ffh written)
    // [32M,64M)  ffh   bf16 [8192][2048]  (step 6, over dead ctxs/qkv)
    // [48M,72M)  qkv   bf16 [8192][1536]  (dead after step 3)
    // [99.1M..]  weights bf16 (wqs|wos|w1s contiguous, then w2s)
    char* ws = (char*)d_ws;
    unsigned short* lnq  = (unsigned short*)ws;
    unsigned short* x1h  = (unsigned short*)(ws + 16777216);
    unsigned short* ctxs = (unsigned short*)(ws + 2 * 16777216);
    unsigned short* qkv  = (unsigned short*)(ws + 3 * 16777216);
    unsigned short* ffh  = (unsigned short*)(ws + 2 * 16777216);
    unsigned short* wqs  = (unsigned short*)(ws + 2 * 16777216 + 67108864);
    unsigned short* wos  = wqs + (size_t)1536 * 512;
    unsigned short* w1s  = wos + (size_t)512 * 512;
    unsigned short* w2s  = w1s + (size_t)2048 * 512;

    // weight conversions: one launch for all four weights
    conv_all<<<1536, 256, 0, stream>>>(w_in, w_out, w_ff1, w_ff2, wqs, w2s);

    // 1. LN1 -> bf16
    ln_kernel<<<MM, 128, 0, stream>>>(x, ln1_g, ln1_b, lnq);

    // 2. QKV -> bf16 qkv   (BK=32 BN=128 fixed swizzle: grid 768, 4 blocks/CU)
    gemm_k32<3><<<dim3(QKV_N / 128, MM / 128), 256, 0, stream>>>(
        lnq, wqs, b_in, qkv, QKV_N, 512);

    // 3. local attention -> bf16 ctx
    attn_kernel<<<dim3(SS / 64, BB, HH), 256, 0, stream>>>(qkv, ctxs);

    // 4. out-proj + residual: x1 = bf16(x + ctx @ out_w^T + b)   (BK=64 BN=64)
    gemm_tile<64, 4><<<dim3(DD / 64, MM / 128), 256, 0, stream>>>(
        ctxs, wos, b_out, x, nullptr, nullptr, x1h, DD, 512);

    // 5. LN2 (bf16 in) -> bf16
    ln_kernel_b<<<MM, 128, 0, stream>>>(x1h, ln2_g, ln2_b, lnq);

    // 6. FF1 + GELU -> bf16 ffh   (BK=32 BN=128 fixed swizzle: grid 1024)
    gemm_k32<2><<<dim3(DFF / 128, MM / 128), 256, 0, stream>>>(
        lnq, w1s, b_ff1, ffh, DFF, 512);

    // 7. FF2 + residual: out = bf2f(x1) + ffh @ ff_w2^T + b   (BK=64 BN=64, K=2048)
    gemm_tile<64, 5><<<dim3(DD / 64, MM / 128), 256, 0, stream>>>(
        ffh, w2s, b_ff2, nullptr, x1h, out, nullptr, DD, 2048);
}

// Round 19
// 117.237 us; speedup vs baseline: 1.0899x; 1.0312x over previous
//
#include <hip/hip_runtime.h>
#include <hip/hip_bf16.h>
#include <math.h>

// Problem constants
#define BB 4
#define SS 2048
#define DD 512
#define HH 8
#define DHH 64
#define DFF 2048
#define MM (BB*SS)          // 8192 rows
#define QKV_N (3*DD)        // 1536

typedef float  f32x4  __attribute__((ext_vector_type(4)));
typedef __bf16 bf16x8 __attribute__((ext_vector_type(8)));
typedef unsigned short us8 __attribute__((ext_vector_type(8)));
typedef unsigned short us4 __attribute__((ext_vector_type(4)));

// ---- bf16 helpers (RNE, finite inputs) ----
__device__ __forceinline__ unsigned short f2bf(float v) {
    unsigned int u = __float_as_uint(v);
    unsigned int r = (u + 0x7fffu + ((u >> 16) & 1u)) >> 16;
    return (unsigned short)r;
}
__device__ __forceinline__ float bf2f(unsigned short h) {
    return __uint_as_float(((unsigned int)h) << 16);
}

__device__ __forceinline__ f32x4 mfma_bf16(us8 a, us8 b, f32x4 c) {
    return __builtin_amdgcn_mfma_f32_16x16x32_bf16(
        __builtin_bit_cast(bf16x8, a), __builtin_bit_cast(bf16x8, b), c, 0, 0, 0);
}

// NOTE: imm offset of global_load_lds applies to BOTH global and LDS addresses
// (round-9 NaN post-mortem) — always pass 0 and advance pointers instead.
__device__ __forceinline__ void gload_lds16(const void* gsrc, void* ldst) {
    __builtin_amdgcn_global_load_lds(
        (const __attribute__((address_space(1))) void*)gsrc,
        (__attribute__((address_space(3))) void*)ldst, 16, 0, 0);
}

// ---------------------------------------------------------------- prep: LN1 + weight conversion (fused)
// blocks [0,4096): LN1, two rows per block (128 thr/row).
// blocks [4096,5632): fp32->bf16 weight conversion (256 units/block).
__global__ __launch_bounds__(256)
void prep_kernel(const float* __restrict__ x, const float* __restrict__ ln1_g,
                 const float* __restrict__ ln1_b, unsigned short* __restrict__ lnq,
                 const float* __restrict__ w_in, const float* __restrict__ w_out,
                 const float* __restrict__ w_ff1, const float* __restrict__ w_ff2,
                 unsigned short* __restrict__ dst3, unsigned short* __restrict__ dstw2)
{
    const int bidx = blockIdx.x;
    if (bidx < 4096) {
        // -------- LN1: rows bidx*2 + {0,1}
        const int tid = threadIdx.x;
        const int rh  = tid >> 7;                 // row half 0/1
        const int t   = tid & 127;                // lane within row
        const int row = bidx * 2 + rh;
        const float4 v = reinterpret_cast<const float4*>(x + (size_t)row * DD)[t];

        float s  = v.x + v.y + v.z + v.w;
        float s2 = v.x*v.x + v.y*v.y + v.z*v.z + v.w*v.w;
        #pragma unroll
        for (int off = 32; off >= 1; off >>= 1) {
            s  += __shfl_xor(s,  off);
            s2 += __shfl_xor(s2, off);
        }
        __shared__ float red[2][2][2];
        const int lane = t & 63, wid = (t >> 6) & 1;
        if (lane == 0) { red[rh][wid][0] = s; red[rh][wid][1] = s2; }
        __syncthreads();
        const float ts  = red[rh][0][0] + red[rh][1][0];
        const float ts2 = red[rh][0][1] + red[rh][1][1];
        const float mu  = ts * (1.0f / DD);
        const float var = ts2 * (1.0f / DD) - mu * mu;
        const float rs  = rsqrtf(var + 1e-5f);

        const float4 gv = reinterpret_cast<const float4*>(ln1_g)[t];
        const float4 bv = reinterpret_cast<const float4*>(ln1_b)[t];
        us4 hv;
        hv[0] = f2bf((v.x - mu) * rs * gv.x + bv.x);
        hv[1] = f2bf((v.y - mu) * rs * gv.y + bv.y);
        hv[2] = f2bf((v.z - mu) * rs * gv.z + bv.z);
        hv[3] = f2bf((v.w - mu) * rs * gv.w + bv.w);
        *reinterpret_cast<us4*>(lnq + (size_t)row * DD + t * 4) = hv;
    } else {
        // -------- weight conversion
        const int gid = (bidx - 4096) * 256 + threadIdx.x;
        const float* src;
        unsigned short* dst;
        size_t o;
        if (gid < 262144) {
            const int r  = gid >> 6;
            const int k0 = (gid & 63) * 8;
            src = (r < 1536) ? w_in  + (size_t)r * 512 + k0
                : (r < 2048) ? w_out + (size_t)(r - 1536) * 512 + k0
                             : w_ff1 + (size_t)(r - 2048) * 512 + k0;
            o = (size_t)r * 512 + k0;
            dst = dst3;
        } else {
            const int g  = gid - 262144;
            const int r  = g >> 8;
            const int k0 = (g & 255) * 8;
            src = w_ff2 + (size_t)r * 2048 + k0;
            o = (size_t)r * 2048 + k0;
            dst = dstw2;
        }
        us8 h;
        #pragma unroll
        for (int i = 0; i < 8; ++i) h[i] = f2bf(src[i]);
        *reinterpret_cast<us8*>(dst + o) = h;
    }
}

// ---------------------------------------------------------------- LayerNorm (bf16 in) -> bf16
__global__ __launch_bounds__(128)
void ln_kernel_b(const unsigned short* __restrict__ x, const float* __restrict__ g,
                 const float* __restrict__ beta, unsigned short* __restrict__ outp)
{
    const int row = blockIdx.x;
    const int t = threadIdx.x;               // 128 threads, 4 bf16 each
    const us4 hv_in = reinterpret_cast<const us4*>(x + (size_t)row * DD)[t];
    float v0 = bf2f(hv_in[0]), v1 = bf2f(hv_in[1]), v2 = bf2f(hv_in[2]), v3 = bf2f(hv_in[3]);

    float s  = v0 + v1 + v2 + v3;
    float s2 = v0*v0 + v1*v1 + v2*v2 + v3*v3;
    #pragma unroll
    for (int off = 32; off >= 1; off >>= 1) {
        s  += __shfl_xor(s,  off);
        s2 += __shfl_xor(s2, off);
    }
    __shared__ float red[2][2];
    const int lane = t & 63, wid = t >> 6;
    if (lane == 0) { red[wid][0] = s; red[wid][1] = s2; }
    __syncthreads();
    const float ts  = red[0][0] + red[1][0];
    const float ts2 = red[0][1] + red[1][1];
    const float mu  = ts * (1.0f / DD);
    const float var = ts2 * (1.0f / DD) - mu * mu;
    const float rs  = rsqrtf(var + 1e-5f);

    const float4 gv = reinterpret_cast<const float4*>(g)[t];
    const float4 bv = reinterpret_cast<const float4*>(beta)[t];
    us4 hv;
    hv[0] = f2bf((v0 - mu) * rs * gv.x + bv.x);
    hv[1] = f2bf((v1 - mu) * rs * gv.y + bv.y);
    hv[2] = f2bf((v2 - mu) * rs * gv.z + bv.z);
    hv[3] = f2bf((v3 - mu) * rs * gv.w + bv.w);
    *reinterpret_cast<us4*>(outp + (size_t)row * DD + t * 4) = hv;
}

// ---------------------------------------------------------------- BK=32 BN=128 bf16 GEMM (QKV, FF1)
// BM=128, BN=128, BK=32: 32KB LDS dbuf -> 4 blocks/CU (16 waves).
// Swizzle (fixed round 17): chunk = kc ^ ((row>>2)&3) -> 2-way max (free).
// EPI: 2 = bias+GELU -> bf16 Cs; 3 = bias -> bf16 Cs
template<int EPI>
__global__ __launch_bounds__(256, 4)
void gemm_k32(const unsigned short* __restrict__ Ax, const unsigned short* __restrict__ Wx,
              const float* __restrict__ bias, unsigned short* __restrict__ Cs,
              int N, int K)
{
    constexpr int AUSH = 128 * 32;         // 4096 ush = 8 KB
    __shared__ unsigned short smem[2][2 * AUSH];

    const int tid  = threadIdx.x;
    const int wave = tid >> 6, lane = tid & 63;
    const int wm = wave >> 1, wn = wave & 1;
    const int lr = lane & 15, kc = lane >> 4;

    const int nwg = gridDim.x * gridDim.y;
    int bid = blockIdx.y * gridDim.x + blockIdx.x;
    bid = (bid & 7) * (nwg >> 3) + (bid >> 3);
    const int bn = (bid % gridDim.x) * 128;
    const int bm = (bid / gridDim.x) * 128;

    const int nkb = K >> 5;                // 16 for K=512 (even)

    int aoff[4], woff[4];
    #pragma unroll
    for (int m = 0; m < 4; ++m) {
        const int ra = wm * 64 + m * 16 + lr;
        aoff[m] = ra * 32 + ((kc ^ ((ra >> 2) & 3)) * 8);
    }
    #pragma unroll
    for (int n = 0; n < 4; ++n) {
        const int rw = wn * 64 + n * 16 + lr;
        woff[n] = AUSH + rw * 32 + ((kc ^ ((rw >> 2) & 3)) * 8);
    }

    f32x4 acc[4][4];
    #pragma unroll
    for (int i = 0; i < 4; ++i)
        #pragma unroll
        for (int j = 0; j < 4; ++j) acc[i][j] = (f32x4){0.f, 0.f, 0.f, 0.f};

    // staging pointers; source chunk = LDS slot ^ ((row>>2)&3)
    const unsigned short* aP[2];
    const unsigned short* wP[2];
    #pragma unroll
    for (int j = 0; j < 2; ++j) {
        const int off = j * 2048 + tid * 8;
        const int row = off >> 5;
        const int q   = ((off >> 3) & 3) ^ ((row >> 2) & 3);
        aP[j] = Ax + (size_t)(bm + row) * K + q * 8;
        wP[j] = Wx + (size_t)(bn + row) * K + q * 8;
    }

#define STAGE_T(BUF) do {                                                      \
        _Pragma("unroll")                                                      \
        for (int j = 0; j < 2; ++j) {                                          \
            gload_lds16(aP[j], &smem[BUF][j * 2048 + tid * 8]);                \
            gload_lds16(wP[j], &smem[BUF][AUSH + j * 2048 + tid * 8]);         \
        }                                                                      \
    } while (0)

#define ADV_T() do {                                                           \
        _Pragma("unroll")                                                      \
        for (int j = 0; j < 2; ++j) { aP[j] += 32; wP[j] += 32; }              \
    } while (0)

#define COMPUTE_T(BUF) do {                                                    \
        const unsigned short* S = smem[BUF];                                   \
        us8 a[4], w[4];                                                        \
        _Pragma("unroll")                                                      \
        for (int m = 0; m < 4; ++m)                                            \
            a[m] = *reinterpret_cast<const us8*>(S + aoff[m]);                 \
        _Pragma("unroll")                                                      \
        for (int n = 0; n < 4; ++n)                                            \
            w[n] = *reinterpret_cast<const us8*>(S + woff[n]);                 \
        _Pragma("unroll")                                                      \
        for (int m = 0; m < 4; ++m)                                            \
            _Pragma("unroll")                                                  \
            for (int n = 0; n < 4; ++n)                                        \
                acc[m][n] = mfma_bf16(a[m], w[n], acc[m][n]);                  \
    } while (0)

    STAGE_T(0); ADV_T();
    for (int kb = 0; kb < nkb; kb += 2) {
        __syncthreads();
        STAGE_T(1); ADV_T();
        COMPUTE_T(0);
        __syncthreads();
        if (kb + 2 < nkb) STAGE_T(0);
        ADV_T();
        COMPUTE_T(1);
    }
#undef STAGE_T
#undef ADV_T
#undef COMPUTE_T

    // epilogue; C/D layout: col = lane&15, row = (lane>>4)*4 + reg
    float bvn[4];
    #pragma unroll
    for (int n = 0; n < 4; ++n) bvn[n] = bias[bn + wn * 64 + n * 16 + lr];

    #pragma unroll
    for (int m = 0; m < 4; ++m) {
        #pragma unroll
        for (int j = 0; j < 4; ++j) {
            const int row = bm + wm * 64 + m * 16 + kc * 4 + j;
            #pragma unroll
            for (int n = 0; n < 4; ++n) {
                const int col = bn + wn * 64 + n * 16 + lr;
                float v = acc[m][n][j] + bvn[n];
                if constexpr (EPI == 2)
                    v = 0.5f * v * (1.0f + erff(v * 0.70710678118654752f));
                Cs[(size_t)row * N + col] = f2bf(v);
            }
        }
    }
}

// ---------------------------------------------------------------- BN=64 BK=64 bf16 GEMM (oproj, FF2)
// Conflict-free 8-chunk swizzle; 48KB LDS -> 3 blocks/CU; 2-barrier dbuf, x2-unrolled.
// EPI: 4 = bias + Resf(fp32) -> bf16 Cs; 5 = bias + Resh(bf16) -> fp32 Cf
template<int BN, int EPI>
__global__ __launch_bounds__(256, 3)
void gemm_tile(const unsigned short* __restrict__ Ax, const unsigned short* __restrict__ Wx,
               const float* __restrict__ bias,
               const float* __restrict__ Resf, const unsigned short* __restrict__ Resh,
               float* __restrict__ Cf, unsigned short* __restrict__ Cs,
               int N, int K)
{
    constexpr int NF   = BN / 32;
    constexpr int NB   = BN / 32;
    constexpr int AUSH = 128 * 64;
    constexpr int BUSH = BN * 64;
    __shared__ unsigned short smem[2][AUSH + BUSH];

    const int tid  = threadIdx.x;
    const int wave = tid >> 6, lane = tid & 63;
    const int wm = wave >> 1, wn = wave & 1;
    const int lr = lane & 15, kc = lane >> 4;

    const int nwg = gridDim.x * gridDim.y;
    int bid = blockIdx.y * gridDim.x + blockIdx.x;
    bid = (bid & 7) * (nwg >> 3) + (bid >> 3);
    const int bn = (bid % gridDim.x) * BN;
    const int bm = (bid / gridDim.x) * 128;

    const int nkb = K >> 6;

    int aoff[4], woff[NF];
    #pragma unroll
    for (int m = 0; m < 4; ++m) {
        const int ra = wm * 64 + m * 16 + lr;
        aoff[m] = ra * 64 + ((kc ^ (ra & 7)) * 8);
    }
    #pragma unroll
    for (int n = 0; n < NF; ++n) {
        const int rw = wn * (NF * 16) + n * 16 + lr;
        woff[n] = AUSH + rw * 64 + ((kc ^ (rw & 7)) * 8);
    }

    f32x4 acc[4][NF];
    #pragma unroll
    for (int i = 0; i < 4; ++i)
        #pragma unroll
        for (int j = 0; j < NF; ++j) acc[i][j] = (f32x4){0.f, 0.f, 0.f, 0.f};

    const unsigned short* aP[4];
    const unsigned short* wP[NB];
    #pragma unroll
    for (int j = 0; j < 4; ++j) {
        const int off = j * 2048 + tid * 8;
        const int row = off >> 6;
        const int q   = ((off >> 3) & 7) ^ (row & 7);
        aP[j] = Ax + (size_t)(bm + row) * K + q * 8;
    }
    #pragma unroll
    for (int j = 0; j < NB; ++j) {
        const int off = j * 2048 + tid * 8;
        const int row = off >> 6;
        const int q   = ((off >> 3) & 7) ^ (row & 7);
        wP[j] = Wx + (size_t)(bn + row) * K + q * 8;
    }

#define STAGE_T(BUF) do {                                                      \
        _Pragma("unroll")                                                      \
        for (int j = 0; j < 4; ++j)                                            \
            gload_lds16(aP[j], &smem[BUF][j * 2048 + tid * 8]);                \
        _Pragma("unroll")                                                      \
        for (int j = 0; j < NB; ++j)                                           \
            gload_lds16(wP[j], &smem[BUF][AUSH + j * 2048 + tid * 8]);         \
    } while (0)

#define ADV_T() do {                                                           \
        _Pragma("unroll")                                                      \
        for (int j = 0; j < 4; ++j) aP[j] += 64;                               \
        _Pragma("unroll")                                                      \
        for (int j = 0; j < NB; ++j) wP[j] += 64;                              \
    } while (0)

#define COMPUTE_T(BUF) do {                                                    \
        const unsigned short* S = smem[BUF];                                   \
        us8 a0[4], a1[4], w0[NF], w1[NF];                                      \
        _Pragma("unroll")                                                      \
        for (int m = 0; m < 4; ++m) {                                          \
            a0[m] = *reinterpret_cast<const us8*>(S + aoff[m]);                \
            a1[m] = *reinterpret_cast<const us8*>(S + (aoff[m] ^ 32));         \
        }                                                                      \
        _Pragma("unroll")                                                      \
        for (int n = 0; n < NF; ++n) {                                         \
            w0[n] = *reinterpret_cast<const us8*>(S + woff[n]);                \
            w1[n] = *reinterpret_cast<const us8*>(S + (woff[n] ^ 32));         \
        }                                                                      \
        _Pragma("unroll")                                                      \
        for (int m = 0; m < 4; ++m)                                            \
            _Pragma("unroll")                                                  \
            for (int n = 0; n < NF; ++n) {                                     \
                acc[m][n] = mfma_bf16(a0[m], w0[n], acc[m][n]);                \
                acc[m][n] = mfma_bf16(a1[m], w1[n], acc[m][n]);                \
            }                                                                  \
    } while (0)

    STAGE_T(0); ADV_T();
    for (int kb = 0; kb < nkb; kb += 2) {
        __syncthreads();
        STAGE_T(1); ADV_T();
        COMPUTE_T(0);
        __syncthreads();
        if (kb + 2 < nkb) STAGE_T(0);
        ADV_T();
        COMPUTE_T(1);
    }
#undef STAGE_T
#undef ADV_T
#undef COMPUTE_T

    float bvn[NF];
    #pragma unroll
    for (int n = 0; n < NF; ++n) bvn[n] = bias[bn + wn * (NF * 16) + n * 16 + lr];

    #pragma unroll
    for (int m = 0; m < 4; ++m) {
        #pragma unroll
        for (int j = 0; j < 4; ++j) {
            const int row = bm + wm * 64 + m * 16 + kc * 4 + j;
            #pragma unroll
            for (int n = 0; n < NF; ++n) {
                const int col = bn + wn * (NF * 16) + n * 16 + lr;
                float v = acc[m][n][j] + bvn[n];
                if constexpr (EPI == 4) {
                    v += Resf[(size_t)row * N + col];
                    Cs[(size_t)row * N + col] = f2bf(v);
                } else {   // EPI == 5
                    v += bf2f(Resh[(size_t)row * N + col]);
                    Cf[(size_t)row * N + col] = v;
                }
            }
        }
    }
}

// ---------------------------------------------------------------- Local attention (bf16 qkv in, bf16 out)
__global__ __launch_bounds__(256)
void attn_kernel(const unsigned short* __restrict__ qkv, unsigned short* __restrict__ ctx)
{
    constexpr int RAD = 4;
    constexpr int TQ  = 64;
    constexpr int KROWS = TQ + 2 * RAD;   // 72
    constexpr int LDK = DHH + 4;          // 68

    __shared__ float Ks[KROWS][LDK];
    __shared__ float Vs[KROWS][LDK];

    const int t  = threadIdx.x;
    const int qt = blockIdx.x;
    const int b  = blockIdx.y;
    const int h  = blockIdx.z;
    const int q0 = qt * TQ;
    const unsigned short* base = qkv + (size_t)(b * SS) * QKV_N + h * DHH;

    for (int idx = t; idx < KROWS * 8; idx += 256) {
        const int row = idx >> 3;
        const int c8  = idx & 7;              // 8 elems per unit
        const int gr  = q0 - RAD + row;
        float kf[8], vf[8];
        if (gr >= 0 && gr < SS) {
            const unsigned short* p = base + (size_t)gr * QKV_N;
            const us8 kv = *reinterpret_cast<const us8*>(p + DD     + c8 * 8);
            const us8 vv = *reinterpret_cast<const us8*>(p + 2 * DD + c8 * 8);
            #pragma unroll
            for (int i = 0; i < 8; ++i) { kf[i] = bf2f(kv[i]); vf[i] = bf2f(vv[i]); }
        } else {
            #pragma unroll
            for (int i = 0; i < 8; ++i) { kf[i] = 0.f; vf[i] = 0.f; }
        }
        #pragma unroll
        for (int i = 0; i < 8; i += 4) {
            *reinterpret_cast<float4*>(&Ks[row][c8 * 8 + i]) =
                make_float4(kf[i], kf[i+1], kf[i+2], kf[i+3]);
            *reinterpret_cast<float4*>(&Vs[row][c8 * 8 + i]) =
                make_float4(vf[i], vf[i+1], vf[i+2], vf[i+3]);
        }
    }
    __syncthreads();

    const int qi   = t >> 2;
    const int quad = t & 3;
    const int gq   = q0 + qi;
    const int d0   = quad * 16;

    const unsigned short* qp = base + (size_t)gq * QKV_N + d0;
    float q[16];
    {
        const us8 qa = *reinterpret_cast<const us8*>(qp);
        const us8 qb = *reinterpret_cast<const us8*>(qp + 8);
        #pragma unroll
        for (int i = 0; i < 8; ++i) { q[i] = bf2f(qa[i]); q[8 + i] = bf2f(qb[i]); }
    }

    float s[9];
    #pragma unroll
    for (int j = 0; j < 9; ++j) {
        const float* kr = &Ks[qi + j][d0];
        float p = 0.f;
        #pragma unroll
        for (int i = 0; i < 16; i += 4) {
            const float4 k4 = *reinterpret_cast<const float4*>(kr + i);
            p += q[i] * k4.x + q[i+1] * k4.y + q[i+2] * k4.z + q[i+3] * k4.w;
        }
        p += __shfl_xor(p, 1);
        p += __shfl_xor(p, 2);
        const int gk = gq + j - RAD;
        s[j] = (gk >= 0 && gk < SS) ? p * 0.125f : -INFINITY;
    }
    float mx = s[0];
    #pragma unroll
    for (int j = 1; j < 9; ++j) mx = fmaxf(mx, s[j]);
    float pr[9]; float l = 0.f;
    #pragma unroll
    for (int j = 0; j < 9; ++j) { pr[j] = __expf(s[j] - mx); l += pr[j]; }
    const float inv = 1.0f / l;

    float o[16];
    #pragma unroll
    for (int i = 0; i < 16; ++i) o[i] = 0.f;
    #pragma unroll
    for (int j = 0; j < 9; ++j) {
        const float pj = pr[j] * inv;
        const float* vr = &Vs[qi + j][d0];
        #pragma unroll
        for (int i = 0; i < 16; i += 4) {
            const float4 v4 = *reinterpret_cast<const float4*>(vr + i);
            o[i]     = fmaf(pj, v4.x, o[i]);
            o[i + 1] = fmaf(pj, v4.y, o[i + 1]);
            o[i + 2] = fmaf(pj, v4.z, o[i + 2]);
            o[i + 3] = fmaf(pj, v4.w, o[i + 3]);
        }
    }
    unsigned short* op = ctx + (size_t)(b * SS + gq) * DD + h * DHH + d0;
    us8 h0, h1;
    #pragma unroll
    for (int i = 0; i < 8; ++i) {
        h0[i] = f2bf(o[i]);
        h1[i] = f2bf(o[8 + i]);
    }
    *reinterpret_cast<us8*>(op)     = h0;
    *reinterpret_cast<us8*>(op + 8) = h1;
}

// ---------------------------------------------------------------- launch
extern "C" void kernel_launch(void* const* d_in, const int* in_sizes, int n_in,
                              void* d_out, int out_size, void* d_ws, size_t ws_size,
                              hipStream_t stream)
{
    const float* x     = (const float*)d_in[0];
    const float* w_in  = (const float*)d_in[1];
    const float* b_in  = (const float*)d_in[2];
    const float* w_out = (const float*)d_in[3];
    const float* b_out = (const float*)d_in[4];
    const float* w_ff1 = (const float*)d_in[5];
    const float* b_ff1 = (const float*)d_in[6];
    const float* w_ff2 = (const float*)d_in[7];
    const float* b_ff2 = (const float*)d_in[8];
    const float* ln1_g = (const float*)d_in[9];
    const float* ln1_b = (const float*)d_in[10];
    const float* ln2_g = (const float*)d_in[11];
    const float* ln2_b = (const float*)d_in[12];
    float* out = (float*)d_out;

    // workspace layout (bytes):
    // [0,16M)    lnq   bf16 [8192][512]   (LN out, reused for LN2)
    // [16M,32M)  x1    bf16 [8192][512]
    // [32M,48M)  ctxs  bf16 [8192][512]   (dead before ffh written)
    // [32M,64M)  ffh   bf16 [8192][2048]  (step 6, over dead ctxs/qkv)
    // [48M,72M)  qkv   bf16 [8192][1536]  (dead after step 3)
    // [99.1M..]  weights bf16 (wqs|wos|w1s contiguous, then w2s)
    char* ws = (char*)d_ws;
    unsigned short* lnq  = (unsigned short*)ws;
    unsigned short* x1h  = (unsigned short*)(ws + 16777216);
    unsigned short* ctxs = (unsigned short*)(ws + 2 * 16777216);
    unsigned short* qkv  = (unsigned short*)(ws + 3 * 16777216);
    unsigned short* ffh  = (unsigned short*)(ws + 2 * 16777216);
    unsigned short* wqs  = (unsigned short*)(ws + 2 * 16777216 + 67108864);
    unsigned short* wos  = wqs + (size_t)1536 * 512;
    unsigned short* w1s  = wos + (size_t)512 * 512;
    unsigned short* w2s  = w1s + (size_t)2048 * 512;

    // 1. fused prep: LN1 (blocks 0..4095) + all weight conversions (blocks 4096..5631)
    prep_kernel<<<5632, 256, 0, stream>>>(x, ln1_g, ln1_b, lnq,
                                          w_in, w_out, w_ff1, w_ff2, wqs, w2s);

    // 2. QKV -> bf16 qkv   (BK=32 BN=128: grid 768, 4 blocks/CU)
    gemm_k32<3><<<dim3(QKV_N / 128, MM / 128), 256, 0, stream>>>(
        lnq, wqs, b_in, qkv, QKV_N, 512);

    // 3. local attention -> bf16 ctx
    attn_kernel<<<dim3(SS / 64, BB, HH), 256, 0, stream>>>(qkv, ctxs);

    // 4. out-proj + residual: x1 = bf16(x + ctx @ out_w^T + b)   (BK=64 BN=64)
    gemm_tile<64, 4><<<dim3(DD / 64, MM / 128), 256, 0, stream>>>(
        ctxs, wos, b_out, x, nullptr, nullptr, x1h, DD, 512);

    // 5. LN2 (bf16 in) -> bf16
    ln_kernel_b<<<MM, 128, 0, stream>>>(x1h, ln2_g, ln2_b, lnq);

    // 6. FF1 + GELU -> bf16 ffh   (BK=32 BN=128: grid 1024)
    gemm_k32<2><<<dim3(DFF / 128, MM / 128), 256, 0, stream>>>(
        lnq, w1s, b_ff1, ffh, DFF, 512);

    // 7. FF2 + residual: out = bf2f(x1) + ffh @ ff_w2^T + b   (BK=64 BN=64, K=2048)
    gemm_tile<64, 5><<<dim3(DD / 64, MM / 128), 256, 0, stream>>>(
        ffh, w2s, b_ff2, nullptr, x1h, out, nullptr, DD, 2048);
}